// Round 11
// baseline (665.850 us; speedup 1.0000x reference)
//
#include <hip/hip_runtime.h>
#include <hip/hip_bf16.h>

typedef unsigned short u16;
typedef __bf16 bf16x8 __attribute__((ext_vector_type(8)));
typedef float f32x4 __attribute__((ext_vector_type(4)));

#define DEVI __device__ __forceinline__

DEVI u16 f2bf(float f) {
    unsigned u = __builtin_bit_cast(unsigned, f);
    u += 0x7fff + ((u >> 16) & 1);   // RNE; inputs are finite
    return (u16)(u >> 16);
}
DEVI float bf2f(u16 h) {
    unsigned u = ((unsigned)h) << 16;
    return __builtin_bit_cast(float, u);
}

typedef __attribute__((address_space(1))) const unsigned GU32;
typedef __attribute__((address_space(3))) unsigned LU32;

DEVI void gload_lds16(const void* g, void* l) {
    __builtin_amdgcn_global_load_lds((GU32*)g, (LU32*)l, 16, 0, 0);
}

// Bijective XCD-chunk swizzle (m204): XCD x owns L in [x*(N/8), (x+1)*(N/8)).
DEVI int xcd_swz(int orig, int n) {
    int q = n >> 3, r = n & 7, x = orig & 7, o = orig >> 3;
    return (x < r ? x * (q + 1) : r * (q + 1) + (x - r) * q) + o;
}

// ===========================================================================
// 256x256 GEMM, m201-faithful 8-phase schedule (plain HIP port).
//   C[256x256] += A[MxK] * B^T  (B stored N x K row-major), BK=64.
//   512 thr = 8 waves (2M x 4N); wave tile 128x64; acc[8][4] f32x4 of
//   mfma_f32_16x16x32_bf16  (acc[mh*4+mi][nj]: rows wr*128+mh*64+mi*16+..).
//   LDS = [buf2][mat2][kh2] regions of 16KB (256 rows x 32 cols bf16,
//   row stride 64B, T2 XOR swizzle) = 128 KiB.
//   Per K-tile T (buf c=T&1): 4 phases (mh,kh) = (0,0),(1,0),(0,1),(1,1):
//     ph: {ds_read A-sub [4 b128] (+B [4 b128] when kh enters, reused at mh1);
//          stage ONE half-tile of T+1 (2 gloads);
//          s_barrier(alpha); lgkmcnt(0); sched_barrier;
//          setprio1; 16 MFMA (acc-half mh x kh); setprio0;
//          [ph1: vmcnt(4) -> confirms THIS tile's kh1 (vmcnt(0) if last)]
//          [ph3: vmcnt(4) -> confirms T+1's kh0]
//          s_barrier(beta); sched_barrier}
//   Invariants verified: stage lead = 1 tile, 4 loads left in flight at each
//   confirm point; reads occur after the beta that published their region;
//   stages overwrite regions whose readers drained >=1 beta earlier.
// ===========================================================================
DEVI void gemm8p(const u16* __restrict__ A, int lda,
                 const u16* __restrict__ B, int ldb,
                 int NT, int m0, int n0, u16* lds, f32x4 (&acc)[8][4])
{
    const int tid = threadIdx.x;
    const int wave = tid >> 6, lane = tid & 63;
    const int lr = lane & 15, lq = lane >> 4;
    const int wr = wave >> 2, wc = wave & 3;

    // Swizzled ds_read byte offsets (region-relative).
    int offA[2][4], offB[4];
    #pragma unroll
    for (int mh = 0; mh < 2; ++mh)
        #pragma unroll
        for (int mi = 0; mi < 4; ++mi) {
            int ra = wr * 128 + mh * 64 + mi * 16 + lr;
            offA[mh][mi] = ra * 64 + ((lq * 16) ^ (((ra >> 1) & 3) << 4));
        }
    #pragma unroll
    for (int nj = 0; nj < 4; ++nj) {
        int rb = wc * 64 + nj * 16 + lr;
        offB[nj] = rb * 64 + ((lq * 16) ^ (((rb >> 1) & 3) << 4));
    }

    // Staging: thread t -> rows t>>2 and 128+(t>>2), 16B chunk (t&3);
    // source column inverse-swizzled ((r>>1)&3 == (t>>3)&3, +128-invariant).
    // Pointers advance +32 per staged kh (stage order kh0,kh1 per tile).
    const int rs = tid >> 2;
    const int cl = (tid & 3) ^ ((tid >> 3) & 3);
    const u16* pA = A + (size_t)(m0 + rs) * lda + cl * 8;
    const u16* pB = B + (size_t)(n0 + rs) * ldb + cl * 8;
    const size_t a2 = (size_t)128 * lda, b2 = (size_t)128 * ldb;
    const int t8 = tid * 8;

    auto reg = [&](int c, int mat, int kh) -> u16* {
        return lds + (((c * 2 + mat) * 2 + kh) << 13);   // 8192 u16 per region
    };

#define STA(c, kh) do { u16* d_ = reg(c, 0, kh); \
        gload_lds16(pA, d_ + t8); gload_lds16(pA + a2, d_ + 4096 + t8); pA += 32; } while (0)
#define STB(c, kh) do { u16* d_ = reg(c, 1, kh); \
        gload_lds16(pB, d_ + t8); gload_lds16(pB + b2, d_ + 4096 + t8); pB += 32; } while (0)
#define SBAR()  __builtin_amdgcn_s_barrier()
#define SCHED() __builtin_amdgcn_sched_barrier(0)
#define LGKM0() do { asm volatile("s_waitcnt lgkmcnt(0)" ::: "memory"); SCHED(); } while (0)

    // Prologue: stage tile 0 (kh0: A,B then kh1: A,B = 8 loads);
    // confirm kh0 pair (leave kh1's 4 in flight = steady-state leftover).
    STA(0, 0); STB(0, 0); STA(0, 1); STB(0, 1);
    asm volatile("s_waitcnt vmcnt(4)" ::: "memory");
    SBAR(); SCHED();

    for (int T = 0; T < NT; ++T) {
        const int c = T & 1;
        const bool last = (T == NT - 1);
        const char* rA0 = (const char*)reg(c, 0, 0);
        const char* rB0 = (const char*)reg(c, 1, 0);
        const char* rA1 = (const char*)reg(c, 0, 1);
        const char* rB1 = (const char*)reg(c, 1, 1);
        bf16x8 af[4], bv[4];

        // ---------- phase 0: (mh0, kh0) ----------
        #pragma unroll
        for (int mi = 0; mi < 4; ++mi) af[mi] = *(const bf16x8*)(rA0 + offA[0][mi]);
        #pragma unroll
        for (int nj = 0; nj < 4; ++nj) bv[nj] = *(const bf16x8*)(rB0 + offB[nj]);
        if (!last) STA(c ^ 1, 0);
        SBAR(); LGKM0();
        __builtin_amdgcn_s_setprio(1);
        #pragma unroll
        for (int mi = 0; mi < 4; ++mi)
            #pragma unroll
            for (int nj = 0; nj < 4; ++nj)
                acc[mi][nj] = __builtin_amdgcn_mfma_f32_16x16x32_bf16(af[mi], bv[nj], acc[mi][nj], 0, 0, 0);
        __builtin_amdgcn_s_setprio(0);
        SBAR(); SCHED();

        // ---------- phase 1: (mh1, kh0), B reused ----------
        #pragma unroll
        for (int mi = 0; mi < 4; ++mi) af[mi] = *(const bf16x8*)(rA0 + offA[1][mi]);
        if (!last) STB(c ^ 1, 0);
        SBAR(); LGKM0();
        __builtin_amdgcn_s_setprio(1);
        #pragma unroll
        for (int mi = 0; mi < 4; ++mi)
            #pragma unroll
            for (int nj = 0; nj < 4; ++nj)
                acc[4 + mi][nj] = __builtin_amdgcn_mfma_f32_16x16x32_bf16(af[mi], bv[nj], acc[4 + mi][nj], 0, 0, 0);
        __builtin_amdgcn_s_setprio(0);
        // Confirm THIS tile's kh1 pair (staged longest ago among in-flight).
        if (last) { asm volatile("s_waitcnt vmcnt(0)" ::: "memory"); }
        else      { asm volatile("s_waitcnt vmcnt(4)" ::: "memory"); }
        SBAR(); SCHED();

        // ---------- phase 2: (mh0, kh1) ----------
        #pragma unroll
        for (int mi = 0; mi < 4; ++mi) af[mi] = *(const bf16x8*)(rA1 + offA[0][mi]);
        #pragma unroll
        for (int nj = 0; nj < 4; ++nj) bv[nj] = *(const bf16x8*)(rB1 + offB[nj]);
        if (!last) STA(c ^ 1, 1);
        SBAR(); LGKM0();
        __builtin_amdgcn_s_setprio(1);
        #pragma unroll
        for (int mi = 0; mi < 4; ++mi)
            #pragma unroll
            for (int nj = 0; nj < 4; ++nj)
                acc[mi][nj] = __builtin_amdgcn_mfma_f32_16x16x32_bf16(af[mi], bv[nj], acc[mi][nj], 0, 0, 0);
        __builtin_amdgcn_s_setprio(0);
        SBAR(); SCHED();

        // ---------- phase 3: (mh1, kh1), B reused ----------
        #pragma unroll
        for (int mi = 0; mi < 4; ++mi) af[mi] = *(const bf16x8*)(rA1 + offA[1][mi]);
        if (!last) STB(c ^ 1, 1);
        SBAR(); LGKM0();
        __builtin_amdgcn_s_setprio(1);
        #pragma unroll
        for (int mi = 0; mi < 4; ++mi)
            #pragma unroll
            for (int nj = 0; nj < 4; ++nj)
                acc[4 + mi][nj] = __builtin_amdgcn_mfma_f32_16x16x32_bf16(af[mi], bv[nj], acc[4 + mi][nj], 0, 0, 0);
        __builtin_amdgcn_s_setprio(0);
        // Confirm T+1's kh0 pair before its phase 0.
        if (!last) { asm volatile("s_waitcnt vmcnt(4)" ::: "memory"); }
        SBAR(); SCHED();
    }
#undef STA
#undef STB
#undef SBAR
#undef SCHED
#undef LGKM0
}

// Output coords: row = m0 + wr*128 + (a>>2)*64 + (a&3)*16 + lq*4 + rr,
//                col = n0 + wc*64 + nj*16 + lr       (16x16 C/D, m89)
#define EPI_COORDS()                                        \
    const int tid = threadIdx.x;                            \
    const int wave = tid >> 6, lane = tid & 63;             \
    const int lr = lane & 15, lq = lane >> 4;               \
    const int wr = wave >> 2, wc = wave & 3;                \
    (void)tid;

// ---------------------------------------------------------------------------
// Prep kernels
// ---------------------------------------------------------------------------
__global__ __launch_bounds__(256) void k_cast_x(const float* __restrict__ x, u16* __restrict__ xb)
{
    size_t i = (size_t)blockIdx.x * 256 + threadIdx.x;
    float4 f = ((const float4*)x)[i];
    ushort4 o;
    o.x = f2bf(f.x); o.y = f2bf(f.y); o.z = f2bf(f.z); o.w = f2bf(f.w);
    ((ushort4*)xb)[i] = o;
}

// in: R x C f32 row-major -> out: Cout x R bf16 row-major, zero-fill c >= C.
__global__ void k_transpose_w(const float* __restrict__ in, u16* __restrict__ out, int R, int C)
{
    __shared__ u16 t[32][33];
    int c0 = blockIdx.x * 32, r0 = blockIdx.y * 32;
    int tx = threadIdx.x, ty = threadIdx.y;
    #pragma unroll
    for (int p = 0; p < 4; ++p) {
        int rr = ty + p * 8;
        int c = c0 + tx;
        t[rr][tx] = (c < C) ? f2bf(in[(size_t)(r0 + rr) * C + c]) : (u16)0;
    }
    __syncthreads();
    #pragma unroll
    for (int p = 0; p < 4; ++p) {
        int cc = ty + p * 8;
        out[(size_t)(c0 + cc) * R + r0 + tx] = t[tx][cc];
    }
}

// ---------------------------------------------------------------------------
// GEMM1: h = x@Wi (raw acc, bf16) -> h[16384][3328].
// Grid 832 = 64m x 13n. XCD chunk: 8m x 13n (A-chunk 3.1MB, L2-fit).
// ---------------------------------------------------------------------------
__global__ __launch_bounds__(512, 2) void k_gemm1(
    const u16* __restrict__ xb, const u16* __restrict__ WibT, u16* __restrict__ h)
{
    __shared__ __align__(16) u16 lds[8 * 8192];
    f32x4 acc[8][4] = {};
    int L = xcd_swz(blockIdx.x, 832);
    int xcd = L / 104, loc = L % 104;
    int m0 = (xcd * 8 + loc % 8) * 256, n0 = (loc / 8) * 256;
    gemm8p(xb, 768, WibT, 768, 12, m0, n0, lds, acc);

    EPI_COORDS();
    #pragma unroll
    for (int a = 0; a < 8; ++a)
        #pragma unroll
        for (int nj = 0; nj < 4; ++nj)
            #pragma unroll
            for (int rr = 0; rr < 4; ++rr) {
                int m = m0 + wr * 128 + (a >> 2) * 64 + (a & 3) * 16 + lq * 4 + rr;
                int n = n0 + wc * 64 + nj * 16 + lr;
                h[(size_t)m * 3328 + n] = f2bf(acc[a][nj][rr]);
            }
}

// ---------------------------------------------------------------------------
// Split pass: silu(h+bi) -> u in-place, vT (transposed), q/k (affine).
// ---------------------------------------------------------------------------
__global__ __launch_bounds__(256) void k_split(
    u16* __restrict__ h, const float* __restrict__ bi,
    const float* __restrict__ gq, const float* __restrict__ bq,
    const float* __restrict__ gk, const float* __restrict__ bk,
    u16* __restrict__ vT, u16* __restrict__ pq, u16* __restrict__ pk)
{
    const int m0 = blockIdx.x * 64, n0 = blockIdx.y * 64;
    const int tid = threadIdx.x;
    const int rrow = tid >> 2, c0 = (tid & 3) * 16;

    if (n0 < 1536) {                       // u region: in-place silu
        size_t base = (size_t)(m0 + rrow) * 3328 + n0 + c0;
        #pragma unroll
        for (int g = 0; g < 2; ++g) {
            bf16x8 hv = *(const bf16x8*)(h + base + g * 8);
            u16 ov[8];
            #pragma unroll
            for (int e = 0; e < 8; ++e) {
                float val = (float)hv[e] + bi[n0 + c0 + g * 8 + e];
                ov[e] = f2bf(val / (1.f + __expf(-val)));
            }
            *(uint4*)(h + base + g * 8) = *(const uint4*)ov;
        }
    } else if (n0 < 3072) {                // v region: silu + transpose -> vT
        __shared__ u16 t[64][72];
        size_t base = (size_t)(m0 + rrow) * 3328 + n0 + c0;
        #pragma unroll
        for (int g = 0; g < 2; ++g) {
            bf16x8 hv = *(const bf16x8*)(h + base + g * 8);
            #pragma unroll
            for (int e = 0; e < 8; ++e) {
                float val = (float)hv[e] + bi[n0 + c0 + g * 8 + e];
                t[rrow][c0 + g * 8 + e] = f2bf(val / (1.f + __expf(-val)));
            }
        }
        __syncthreads();
        const int b = m0 >> 12, mm = m0 & 4095, d0 = n0 - 1536;
        #pragma unroll
        for (int p = 0; p < 2; ++p) {
            int dr = (tid >> 3) + p * 32;
            int nc = (tid & 7) * 8;
            u16 tmp[8];
            #pragma unroll
            for (int e = 0; e < 8; ++e) tmp[e] = t[nc + e][dr];
            *(uint4*)(vT + (size_t)b * 1536 * 4096 + (size_t)(d0 + dr) * 4096 + mm + nc) = *(const uint4*)tmp;
        }
    } else {                               // qk region: silu + affine
        size_t base = (size_t)(m0 + rrow) * 3328 + n0 + c0;
        int cb = n0 + c0 - 3072;
        u16 qv[16], kv[16];
        #pragma unroll
        for (int g = 0; g < 2; ++g) {
            bf16x8 hv = *(const bf16x8*)(h + base + g * 8);
            #pragma unroll
            for (int e = 0; e < 8; ++e) {
                int c = cb + g * 8 + e;
                float val = (float)hv[e] + bi[3072 + c];
                float s = val / (1.f + __expf(-val));
                qv[g * 8 + e] = f2bf(s * gq[c] + bq[c]);
                kv[g * 8 + e] = f2bf(s * gk[c] + bk[c]);
            }
        }
        size_t ob = (size_t)(m0 + rrow) * 128 + cb;
        *(uint4*)(pq + ob)     = *(const uint4*)qv;
        *(uint4*)(pq + ob + 8) = *(const uint4*)(qv + 8);
        *(uint4*)(pk + ob)     = *(const uint4*)kv;
        *(uint4*)(pk + ob + 8) = *(const uint4*)(kv + 8);
    }
}

// ---------------------------------------------------------------------------
// Scores: P = relu(q@k^T / sqrt(128))^2 / 4096, ONE batch per launch.
// Grid 256 = 16m x 16n. XCD chunk 2m x 16n.
// ---------------------------------------------------------------------------
__global__ __launch_bounds__(512, 2) void k_scores(
    const u16* __restrict__ q, const u16* __restrict__ k, u16* __restrict__ P, int b)
{
    __shared__ __align__(16) u16 lds[8 * 8192];
    f32x4 acc[8][4] = {};
    const u16* A = q + (size_t)b * 4096 * 128;
    const u16* B = k + (size_t)b * 4096 * 128;
    int L = xcd_swz(blockIdx.x, 256);
    int xcd = L / 32, loc = L % 32;
    int m0 = (xcd * 2 + loc % 2) * 256, n0 = (loc / 2) * 256;
    gemm8p(A, 128, B, 128, 2, m0, n0, lds, acc);

    const float sc = 1.f / (128.f * 4096.f);
    EPI_COORDS();
    #pragma unroll
    for (int a = 0; a < 8; ++a)
        #pragma unroll
        for (int nj = 0; nj < 4; ++nj)
            #pragma unroll
            for (int rr = 0; rr < 4; ++rr) {
                int m = m0 + wr * 128 + (a >> 2) * 64 + (a & 3) * 16 + lq * 4 + rr;
                int n = n0 + wc * 64 + nj * 16 + lr;
                float v = fmaxf(acc[a][nj][rr], 0.f);
                P[(size_t)m * 4096 + n] = f2bf(v * v * sc);
            }
}

// ---------------------------------------------------------------------------
// PV: z = P @ v (B = vT); epilogue uz = u * z in place over h's u-region.
// ONE batch per launch. Grid 96 = 16m x 6n. XCD chunk 2m x 6n (A 4.2MB).
// ---------------------------------------------------------------------------
__global__ __launch_bounds__(512, 2) void k_zu(
    const u16* __restrict__ P, const u16* __restrict__ vT, u16* __restrict__ h, int b)
{
    __shared__ __align__(16) u16 lds[8 * 8192];
    f32x4 acc[8][4] = {};
    const u16* B = vT + (size_t)b * 1536 * 4096;    // 1536 x 4096 (N x K)
    int L = xcd_swz(blockIdx.x, 96);
    int xcd = L / 12, loc = L % 12;
    int m0 = (xcd * 2 + loc / 6) * 256, n0 = (loc % 6) * 256;
    gemm8p(P, 4096, B, 4096, 64, m0, n0, lds, acc);

    EPI_COORDS();
    #pragma unroll
    for (int a = 0; a < 8; ++a)
        #pragma unroll
        for (int nj = 0; nj < 4; ++nj)
            #pragma unroll
            for (int rr = 0; rr < 4; ++rr) {
                int m = m0 + wr * 128 + (a >> 2) * 64 + (a & 3) * 16 + lq * 4 + rr;
                int n = n0 + wc * 64 + nj * 16 + lr;
                size_t idx = (size_t)(b * 4096 + m) * 3328 + n;
                h[idx] = f2bf(bf2f(h[idx]) * acc[a][nj][rr]);
            }
}

// ---------------------------------------------------------------------------
// GEMM3: o = (u*z) @ Wo + bo -> f32 out  (A = h's u-region, lda 3328)
// Grid 192 = 64m x 3n. XCD chunk: nj-fast (B 2.3MB stays L2).
// ---------------------------------------------------------------------------
__global__ __launch_bounds__(512, 2) void k_out(
    const u16* __restrict__ h, const u16* __restrict__ WobT,
    const float* __restrict__ bo, float* __restrict__ out)
{
    __shared__ __align__(16) u16 lds[8 * 8192];
    f32x4 acc[8][4] = {};
    int L = xcd_swz(blockIdx.x, 192);
    int xcd = L / 24, loc = L % 24;
    int m0 = (xcd * 8 + loc / 3) * 256, n0 = (loc % 3) * 256;
    gemm8p(h, 3328, WobT, 1536, 24, m0, n0, lds, acc);

    EPI_COORDS();
    #pragma unroll
    for (int a = 0; a < 8; ++a)
        #pragma unroll
        for (int nj = 0; nj < 4; ++nj)
            #pragma unroll
            for (int rr = 0; rr < 4; ++rr) {
                int m = m0 + wr * 128 + (a >> 2) * 64 + (a & 3) * 16 + lq * 4 + rr;
                int n = n0 + wc * 64 + nj * 16 + lr;
                out[(size_t)m * 768 + n] = acc[a][nj][rr] + bo[n];
            }
}

// ---------------------------------------------------------------------------
extern "C" void kernel_launch(void* const* d_in, const int* in_sizes, int n_in,
                              void* d_out, int out_size, void* d_ws, size_t ws_size,
                              hipStream_t stream)
{
    const float* x  = (const float*)d_in[0];
    const float* Wi = (const float*)d_in[1];
    const float* bi = (const float*)d_in[2];
    const float* gq = (const float*)d_in[3];
    const float* bq = (const float*)d_in[4];
    const float* gk = (const float*)d_in[5];
    const float* bk = (const float*)d_in[6];
    const float* Wo = (const float*)d_in[7];
    const float* bo = (const float*)d_in[8];
    float* out = (float*)d_out;

    char* ws = (char*)d_ws;
    size_t off = 0;
    auto alloc = [&](size_t bytes) -> void* {
        void* p = ws + off;
        off += (bytes + 255) & ~(size_t)255;
        return p;
    };
    u16* xb   = (u16*)alloc((size_t)16384 * 768 * 2);
    u16* WibT = (u16*)alloc((size_t)3328 * 768 * 2);     // padded N: 3200 -> 3328
    u16* WobT = (u16*)alloc((size_t)768 * 1536 * 2);
    u16* h    = (u16*)alloc((size_t)16384 * 3328 * 2);   // raw GEMM1 out; u/uz in place
    u16* vT   = (u16*)alloc((size_t)4 * 1536 * 4096 * 2);
    u16* q    = (u16*)alloc((size_t)16384 * 128 * 2);
    u16* k    = (u16*)alloc((size_t)16384 * 128 * 2);
    u16* P    = (u16*)alloc((size_t)4096 * 4096 * 2);    // 1 batch: L3-resident

    k_cast_x<<<dim3(12288), dim3(256), 0, stream>>>(x, xb);
    k_transpose_w<<<dim3(3328 / 32, 768 / 32), dim3(32, 8), 0, stream>>>(Wi, WibT, 768, 3200);
    k_transpose_w<<<dim3(768 / 32, 1536 / 32), dim3(32, 8), 0, stream>>>(Wo, WobT, 1536, 768);

    k_gemm1<<<dim3(832), dim3(512), 0, stream>>>(xb, WibT, h);
    k_split<<<dim3(256, 50), dim3(256), 0, stream>>>(h, bi, gq, bq, gk, bk, vT, q, k);

    for (int b = 0; b < 4; ++b) {
        k_scores<<<dim3(256), dim3(512), 0, stream>>>(q, k, P, b);
        k_zu<<<dim3(96), dim3(512), 0, stream>>>(P, vT, h, b);
    }

    k_out<<<dim3(192), dim3(512), 0, stream>>>(h, WobT, bo, out);
}